// Round 4
// baseline (17791.776 us; speedup 1.0000x reference)
//
#include <hip/hip_runtime.h>
#include <hip/hip_bf16.h>

#define B_DIM 256
#define T_DIM 512
#define IN_DIM 1024
#define HID_DIM 1024
#define BLK 16384

typedef __attribute__((ext_vector_type(8))) short bf16x8;
typedef __attribute__((ext_vector_type(4))) float f32x4;

__device__ __forceinline__ unsigned short f2bf(float v) {
  unsigned int u = __float_as_uint(v);
  unsigned int r = (u + 0x7fffu + ((u >> 16) & 1u)) >> 16;
  return (unsigned short)r;
}

typedef __attribute__((address_space(3))) unsigned int lds_uint;
typedef const __attribute__((address_space(1))) unsigned int g_uint;
__device__ __forceinline__ void gload_lds16(const void* g, void* l) {
  __builtin_amdgcn_global_load_lds((g_uint*)g, (lds_uint*)l, 16, 0, 0);
}
// src includes per-lane offset; dst is wave-uniform base (HW adds lane*16).
__device__ __forceinline__ void glds4(const unsigned char* s, unsigned char* d) {
#pragma unroll
  for (int i = 0; i < 4; ++i) gload_lds16(s + i * 1024, d + i * 1024);
}

__device__ __forceinline__ void spin_ge(unsigned int* p, unsigned int tgt) {
  while (__hip_atomic_fetch_add(p, 0u, __ATOMIC_RELAXED,
                                __HIP_MEMORY_SCOPE_AGENT) < tgt)
    __builtin_amdgcn_s_sleep(2);
  asm volatile("" ::: "memory");
}

__device__ __forceinline__ void waitvm(int n) {
  switch (n) {
    case 12: asm volatile("s_waitcnt vmcnt(12)" ::: "memory"); break;
    case 8:  asm volatile("s_waitcnt vmcnt(8)" ::: "memory"); break;
    case 4:  asm volatile("s_waitcnt vmcnt(4)" ::: "memory"); break;
    default: asm volatile("s_waitcnt vmcnt(0)" ::: "memory"); break;
  }
}

// ---------------------------------------------------------------------------
// Pack W (4 gates, f32 [2048][1024]) -> bf16 swizzled blocks.
// Packed col in a 64-col block: g*16 + h_in. Block (cb, kc): [col 64][k' 128],
// byte = (col*256 + k'*2) ^ ((col&7)<<4)
// ---------------------------------------------------------------------------
__global__ void prep_pack_w(const float* __restrict__ Wi, const float* __restrict__ Wf,
                            const float* __restrict__ Wo, const float* __restrict__ Wc,
                            unsigned char* __restrict__ Wp) {
  const int bid = blockIdx.x;          // cb*16 + kc
  const int cb = bid >> 4, kc = bid & 15;
  const int tid = threadIdx.x;
  const int col = tid & 63;
  const int g = col >> 4, h_in = col & 15;
  const int kq = tid >> 6;
  const float* W = (g == 0) ? Wi : (g == 1) ? Wf : (g == 2) ? Wo : Wc;
  const float* src = W + (size_t)(kc * 128 + kq * 32) * HID_DIM + cb * 16 + h_in;
  unsigned char* dst = Wp + (size_t)bid * BLK;
  const unsigned int xo = (unsigned int)((col & 7) << 4);
#pragma unroll
  for (int b4 = 0; b4 < 4; ++b4) {
    unsigned short u[8];
#pragma unroll
    for (int j = 0; j < 8; ++j)
      u[j] = f2bf(src[(size_t)(b4 * 8 + j) * HID_DIM]);
    uint4 pk;
    pk.x = (unsigned)u[0] | ((unsigned)u[1] << 16);
    pk.y = (unsigned)u[2] | ((unsigned)u[3] << 16);
    pk.z = (unsigned)u[4] | ((unsigned)u[5] << 16);
    pk.w = (unsigned)u[6] | ((unsigned)u[7] << 16);
    unsigned int byte = ((unsigned int)(col * 256 + kq * 64 + b4 * 16)) ^ xo;
    *(uint4*)(dst + byte) = pk;
  }
}

__global__ void prep_bias(const float* __restrict__ bi, const float* __restrict__ bf_,
                          const float* __restrict__ bo, const float* __restrict__ bc,
                          float* __restrict__ bp) {
  int p = blockIdx.x * 256 + threadIdx.x;  // 0..4095
  int cbb = p >> 6, col = p & 63, g = col >> 4, h_in = col & 15;
  const float* b = (g == 0) ? bi : (g == 1) ? bf_ : (g == 2) ? bo : bc;
  bp[p] = b[cbb * 16 + h_in];
}

// Pack x -> bf16 swizzled chunk images: block bid = (t*4+mb)*8+kc.
__global__ void prep_pack_x(const float* __restrict__ x, unsigned char* __restrict__ xp) {
  const int bid = blockIdx.x;
  const int kc = bid & 7, mb = (bid >> 3) & 3, t = bid >> 5;
  const int tid = threadIdx.x;
  const int row = tid >> 2, kseg = tid & 3;
  const float* src = x + ((size_t)(mb * 64 + row) * T_DIM + t) * IN_DIM + kc * 128 + kseg * 32;
  unsigned char* dst = xp + (size_t)bid * BLK;
  const unsigned int xo = (unsigned)((row & 7) << 4);
#pragma unroll
  for (int c4 = 0; c4 < 4; ++c4) {
    float4 f0 = *(const float4*)(src + c4 * 8);
    float4 f1 = *(const float4*)(src + c4 * 8 + 4);
    uint4 pk;
    pk.x = (unsigned)f2bf(f0.x) | ((unsigned)f2bf(f0.y) << 16);
    pk.y = (unsigned)f2bf(f0.z) | ((unsigned)f2bf(f0.w) << 16);
    pk.z = (unsigned)f2bf(f1.x) | ((unsigned)f2bf(f1.y) << 16);
    pk.w = (unsigned)f2bf(f1.z) | ((unsigned)f2bf(f1.w) << 16);
    *(uint4*)(dst + (((unsigned)(row * 256 + kseg * 64 + c4 * 16)) ^ xo)) = pk;
  }
}

// ---------------------------------------------------------------------------
// Wave-specialized persistent LSTM. 256 WGs (1/CU) x 512 threads.
// Waves 0-3 (h-waves): h_{t-1} @ Wh (K=1024), B-frags in registers,
//   A staged via global_load_lds from the h-image ring (acquire fence after
//   flag spin makes plain loads coherent).
// Waves 4-7 (x-waves): Gx[t+1] = x_{t+1} @ Wx into a 2-slot ring (consumed
//   by the SAME WG next step -> no cross-WG sync).
// Shared 8-chunk barrier rhythm; 4-deep LDS rings; counted vmcnt.
// ---------------------------------------------------------------------------
__global__ __launch_bounds__(512, 2) void lstm_ws(
    const unsigned char* __restrict__ xp, const unsigned char* __restrict__ Wq,
    const float* __restrict__ bp, float* gx, unsigned char* hring,
    unsigned int* prodCnt, unsigned int* consCnt, float* __restrict__ out) {
  extern __shared__ unsigned char ring[];  // h bufs [0,64K), x bufs [64K,128K)
  const int wg = blockIdx.x, mb = wg >> 6, cb = wg & 63;
  const int tid = threadIdx.x, lane = tid & 63, w = tid >> 6;
  const bool isH = (w < 4);
  const int wq = w & 3;
  const int fr = lane & 15;
  const unsigned koff2 = (unsigned)((lane >> 4) << 4);
  const int cl = wq * 16 + fr;
  const int rsub = (lane >> 4) * 4;

  // ---- one-time: B fragments into registers (128 VGPR) ----
  bf16x8 Breg[8][4];
  {
    const int hx = isH ? 8 : 0;
#pragma unroll
    for (int kcl = 0; kcl < 8; ++kcl)
#pragma unroll
      for (int ks = 0; ks < 4; ++ks)
        Breg[kcl][ks] = *(const bf16x8*)(
            Wq + ((size_t)(cb * 16 + hx + kcl) << 14) +
            (((unsigned)(cl * 256 + ks * 64 + koff2)) ^ ((unsigned)((cl & 7) << 4))));
  }
  // ---- bias + cell state ----
  const int erow = tid & 63, hb2 = (tid >> 6) * 2;
  float bI[2], bF[2], bO[2], bG[2];
#pragma unroll
  for (int j = 0; j < 2; ++j) {
    bI[j] = bp[cb * 64 + hb2 + j];
    bF[j] = bp[cb * 64 + 16 + hb2 + j];
    bO[j] = bp[cb * 64 + 32 + hb2 + j];
    bG[j] = bp[cb * 64 + 48 + hb2 + j];
  }
  float cr[2] = {0.f, 0.f};

  unsigned char* hbufs = ring;
  unsigned char* xbufs = ring + 65536;
  float* gates = (float*)ring;  // 64x65 f32 overlay on h bufs (post-GEMM)

#pragma unroll 1
  for (int t = -1; t < T_DIM; ++t) {
    const bool hAct = isH && (t >= 1);
    const bool xAct = (!isH) && (t < T_DIM - 1);

    f32x4 acc[4] = {{0.f, 0.f, 0.f, 0.f}, {0.f, 0.f, 0.f, 0.f},
                    {0.f, 0.f, 0.f, 0.f}, {0.f, 0.f, 0.f, 0.f}};
    // h-waves: init acc from Gx[t] (written by own WG last step)
    if (isH && t >= 0) {
      const float* gt = gx + (size_t)(t & 1) * 1048576 + (size_t)wg * 4096;
#pragma unroll
      for (int rb = 0; rb < 4; ++rb)
#pragma unroll
        for (int j = 0; j < 4; ++j)
          acc[rb][j] = gt[(rb * 16 + rsub + j) * 64 + cl];
    }
    // h-waves: wait for producers, then acquire (buffer_inv) so plain
    // global_load_lds sees the fresh h image.
    if (hAct) {
      if (lane == 0) {
        spin_ge(&prodCnt[(t - 1) * 4 + mb], 64u);
        (void)__hip_atomic_load(&prodCnt[(t - 1) * 4 + mb], __ATOMIC_ACQUIRE,
                                __HIP_MEMORY_SCOPE_AGENT);
      }
      __builtin_amdgcn_sched_barrier(0);
    }
    const unsigned char* hA = hring + (size_t)((t + 2) % 3) * 524288 +
                              (size_t)(mb * 8) * BLK + wq * 4096 + lane * 16;
    const unsigned char* xA = xp + ((size_t)((t + 1) * 4 + mb)) * (8 * BLK) +
                              wq * 4096 + lane * 16;
    // prologue: issue chunks 0..2
    if (hAct) {
#pragma unroll
      for (int c = 0; c < 3; ++c)
        glds4(hA + (size_t)c * BLK, hbufs + c * 16384 + wq * 4096);
    }
    if (xAct) {
#pragma unroll
      for (int c = 0; c < 3; ++c)
        glds4(xA + (size_t)c * BLK, xbufs + c * 16384 + wq * 4096);
    }
    // ---- 8-chunk rhythm ----
#pragma unroll
    for (int kc = 0; kc < 8; ++kc) {
      if (kc < 5) {
        if (hAct)
          glds4(hA + (size_t)(kc + 3) * BLK, hbufs + ((kc + 3) & 3) * 16384 + wq * 4096);
        if (xAct)
          glds4(xA + (size_t)(kc + 3) * BLK, xbufs + ((kc + 3) & 3) * 16384 + wq * 4096);
      }
      waitvm(kc < 5 ? 12 : (kc == 5 ? 8 : (kc == 6 ? 4 : 0)));
      __builtin_amdgcn_s_barrier();
      if (hAct || xAct) {
        const unsigned char* Ab = (isH ? hbufs : xbufs) + (kc & 3) * 16384;
#pragma unroll
        for (int ks = 0; ks < 4; ++ks) {
          const unsigned kb2 = (unsigned)ks * 64 + koff2;
#pragma unroll
          for (int rb = 0; rb < 4; ++rb) {
            const unsigned row = (unsigned)(rb * 16 + fr);
            bf16x8 a = *(const bf16x8*)(Ab + ((row * 256 + kb2) ^ ((row & 7) << 4)));
            acc[rb] = __builtin_amdgcn_mfma_f32_16x16x32_bf16(a, Breg[kc][ks], acc[rb], 0, 0, 0);
          }
        }
      }
      __builtin_amdgcn_s_barrier();
    }

    // ---- epilogue ----
    if (isH && t >= 0) {  // gates = acc (= Gx[t] + h@Wh)
#pragma unroll
      for (int rb = 0; rb < 4; ++rb)
#pragma unroll
        for (int j = 0; j < 4; ++j)
          gates[(rb * 16 + rsub + j) * 65 + cl] = acc[rb][j];
    }
    if (xAct) {  // store Gx[t+1] (write-through agent stores: no dirty lines)
      float* gt = gx + (size_t)((t + 1) & 1) * 1048576 + (size_t)wg * 4096;
#pragma unroll
      for (int rb = 0; rb < 4; ++rb)
#pragma unroll
        for (int j = 0; j < 4; ++j)
          __hip_atomic_store(&gt[(rb * 16 + rsub + j) * 64 + cl], acc[rb][j],
                             __ATOMIC_RELAXED, __HIP_MEMORY_SCOPE_AGENT);
    }
    if (t >= 0) {
      __syncthreads();
      float hv[2];
#pragma unroll
      for (int j = 0; j < 2; ++j) {
        int hc = hb2 + j;
        float pi = gates[erow * 65 + hc] + bI[j];
        float pf = gates[erow * 65 + 16 + hc] + bF[j];
        float po = gates[erow * 65 + 32 + hc] + bO[j];
        float pg = gates[erow * 65 + 48 + hc] + bG[j];
        float ig = 1.f / (1.f + __expf(-pi));
        float fg = 1.f / (1.f + __expf(-pf));
        float og = 1.f / (1.f + __expf(-po));
        float gg = 1.f - 2.f / (1.f + __expf(2.f * pg));  // tanh
        float cn = fg * cr[j] + ig * gg;
        cr[j] = cn;
        hv[j] = og * (1.f - 2.f / (1.f + __expf(2.f * cn)));
      }
      // backpressure: slot t%3 reused; ensure step t-2 consumed it
      if (t >= 3) {
        if (tid == 0) spin_ge(&consCnt[(t - 2) * 4 + mb], 64u);
        __syncthreads();
      }
      if (t < T_DIM - 1) {  // store h_t bf16-pair into slot t%3, swizzled
        int hcg = cb * 16 + hb2;
        int kc2 = hcg >> 7, kp = hcg & 127;
        unsigned byte = ((unsigned)(erow * 256 + kp * 2)) ^ ((unsigned)((erow & 7) << 4));
        unsigned pk = (unsigned)f2bf(hv[0]) | ((unsigned)f2bf(hv[1]) << 16);
        unsigned int* hd = (unsigned int*)(hring + (size_t)(t % 3) * 524288 +
                                           (size_t)(mb * 8 + kc2) * BLK + byte);
        __hip_atomic_store(hd, pk, __ATOMIC_RELAXED, __HIP_MEMORY_SCOPE_AGENT);
      }
      asm volatile("s_waitcnt vmcnt(0)" ::: "memory");
      __syncthreads();
      if (tid == 0) {
        if (t < T_DIM - 1)
          __hip_atomic_fetch_add(&prodCnt[t * 4 + mb], 1u, __ATOMIC_RELEASE,
                                 __HIP_MEMORY_SCOPE_AGENT);
        if (t >= 1)
          __hip_atomic_fetch_add(&consCnt[t * 4 + mb], 1u, __ATOMIC_RELAXED,
                                 __HIP_MEMORY_SCOPE_AGENT);
      }
      if (t == T_DIM - 1) {
        size_t gidx = (size_t)(mb * 64 + erow) * HID_DIM + cb * 16 + hb2;
        *(float2*)(out + gidx) = make_float2(hv[0], hv[1]);
        *(float2*)(out + (size_t)B_DIM * HID_DIM + gidx) = make_float2(cr[0], cr[1]);
      }
    } else {  // t == -1: drain Gx[0] stores before step 0 reads them
      asm volatile("s_waitcnt vmcnt(0)" ::: "memory");
      __syncthreads();
    }
  }
}

// ---------------------------------------------------------------------------
// Round-3 fallback (proven): used only if ws_size < NEED_NEW.
// ---------------------------------------------------------------------------
__device__ __forceinline__ void h_load_fb(unsigned long long (&r)[8],
                                          const unsigned char* src) {
#pragma unroll
  for (int p = 0; p < 8; ++p)
    r[p] = __hip_atomic_load((const unsigned long long*)(src + p * 512),
                             __ATOMIC_RELAXED, __HIP_MEMORY_SCOPE_AGENT);
}
__device__ __forceinline__ void h_write_fb(unsigned long long (&r)[8],
                                           unsigned char* dst) {
#pragma unroll
  for (int p = 0; p < 8; ++p)
    *(unsigned long long*)(dst + p * 512) = r[p];
  asm volatile("s_waitcnt lgkmcnt(0)" ::: "memory");
}

__global__ __launch_bounds__(512, 1) void lstm_persist(
    const unsigned char* __restrict__ xp, const unsigned char* __restrict__ Wq,
    const float* __restrict__ bp, unsigned char* hring,
    unsigned int* prodCnt, unsigned int* consCnt, float* __restrict__ out) {
  extern __shared__ unsigned char ring[];
  const int wg = blockIdx.x, mb = wg >> 6, cb = wg & 63;
  const int tid = threadIdx.x, lane = tid & 63, w = tid >> 6;
  const int wr = w >> 2, wc = w & 3;
  const int fr = lane & 15;
  const unsigned koff2 = (unsigned)((lane >> 4) << 4);
  const int erow = tid & 63, hb2 = (tid >> 6) * 2;
  float bI[2], bF[2], bO[2], bG[2];
#pragma unroll
  for (int j = 0; j < 2; ++j) {
    bI[j] = bp[cb * 64 + hb2 + j];
    bF[j] = bp[cb * 64 + 16 + hb2 + j];
    bO[j] = bp[cb * 64 + 32 + hb2 + j];
    bG[j] = bp[cb * 64 + 48 + hb2 + j];
  }
  float cr[2] = {0.f, 0.f};
  const unsigned char* WB = Wq + (size_t)(cb * 16) * BLK;
  unsigned long long hA[8], hB[8];

#pragma unroll 1
  for (int t = 0; t < T_DIM; ++t) {
    const int NC = (t == 0) ? 8 : 16;
    const unsigned char* xA =
        xp + ((size_t)(t * 4 + mb)) * (8 * BLK) + w * 4096 + lane * 16;
    const unsigned char* hSrc =
        hring + (size_t)((t + 2) % 3) * 524288 +
        (size_t)(mb * 8) * BLK + w * 4096 + lane * 8;
    f32x4 acc[2] = {{0.f, 0.f, 0.f, 0.f}, {0.f, 0.f, 0.f, 0.f}};
    auto consume = [&](int buf) {
      const unsigned char* Ab = ring + buf * 32768;
      const unsigned char* Bb = Ab + BLK;
#pragma unroll
      for (int ks = 0; ks < 4; ++ks) {
        const unsigned kb2 = (unsigned)ks * 64 + koff2;
        const unsigned r0 = (unsigned)(wr * 32 + fr), r1 = r0 + 16;
        const unsigned clx = (unsigned)(wc * 16 + fr);
        bf16x8 a0 = *(const bf16x8*)(Ab + ((r0 * 256 + kb2) ^ ((r0 & 7) << 4)));
        bf16x8 a1 = *(const bf16x8*)(Ab + ((r1 * 256 + kb2) ^ ((r1 & 7) << 4)));
        bf16x8 b0 = *(const bf16x8*)(Bb + ((clx * 256 + kb2) ^ ((clx & 7) << 4)));
        acc[0] = __builtin_amdgcn_mfma_f32_16x16x32_bf16(a0, b0, acc[0], 0, 0, 0);
        acc[1] = __builtin_amdgcn_mfma_f32_16x16x32_bf16(a1, b0, acc[1], 0, 0, 0);
      }
    };
    if (w < 4) {
#pragma unroll
      for (int c = 0; c < 3; ++c)
        glds4(xA + (size_t)c * BLK, ring + c * 32768 + (w << 12));
    } else {
#pragma unroll
      for (int c = 0; c < 3; ++c)
        glds4(WB + (size_t)c * BLK + ((w - 4) << 12) + lane * 16,
              ring + c * 32768 + BLK + ((w - 4) << 12));
    }
#pragma unroll 1
    for (int kc = 0; kc < NC; ++kc) {
      const int nx = kc + 3;
      const bool isq = nx < NC;
      if (isq && nx == 8) {
        if (lane == 0) spin_ge(&prodCnt[(t - 1) * 4 + mb], 64u);
        __builtin_amdgcn_sched_barrier(0);
      }
      if (w < 4) {
        if (isq && nx < 8)
          glds4(xA + (size_t)nx * BLK, ring + (nx & 3) * 32768 + (w << 12));
        if (kc + 1 >= 8 && kc + 1 < NC) {
          unsigned char* d = ring + ((kc + 1) & 3) * 32768 + (w << 12) + lane * 8;
          if (((kc + 1) & 1) == 0) h_write_fb(hA, d);
          else h_write_fb(hB, d);
        }
        if (isq && nx >= 8) {
          const unsigned char* s = hSrc + (size_t)(nx - 8) * BLK;
          if ((nx & 1) == 0) h_load_fb(hA, s);
          else h_load_fb(hB, s);
        }
      } else {
        if (isq)
          glds4(WB + (size_t)nx * BLK + ((w - 4) << 12) + lane * 16,
                ring + (nx & 3) * 32768 + BLK + ((w - 4) << 12));
      }
      const int ahead = NC - 1 - kc;
      if (ahead >= 3)      asm volatile("s_waitcnt vmcnt(12)" ::: "memory");
      else if (ahead == 2) asm volatile("s_waitcnt vmcnt(8)" ::: "memory");
      else if (ahead == 1) asm volatile("s_waitcnt vmcnt(4)" ::: "memory");
      else                 asm volatile("s_waitcnt vmcnt(0)" ::: "memory");
      __builtin_amdgcn_s_barrier();
      consume(kc & 3);
      __builtin_amdgcn_s_barrier();
    }
    float* gates = (float*)ring;
#pragma unroll
    for (int m = 0; m < 2; ++m)
#pragma unroll
      for (int j = 0; j < 4; ++j) {
        int row = wr * 32 + m * 16 + (lane >> 4) * 4 + j;
        int col = wc * 16 + fr;
        gates[row * 65 + col] = acc[m][j];
      }
    __syncthreads();
    float hv[2];
#pragma unroll
    for (int j = 0; j < 2; ++j) {
      int hc = hb2 + j;
      float pi = gates[erow * 65 + hc] + bI[j];
      float pf = gates[erow * 65 + 16 + hc] + bF[j];
      float po = gates[erow * 65 + 32 + hc] + bO[j];
      float pg = gates[erow * 65 + 48 + hc] + bG[j];
      float ig = 1.f / (1.f + __expf(-pi));
      float fg = 1.f / (1.f + __expf(-pf));
      float og = 1.f / (1.f + __expf(-po));
      float gg = 1.f - 2.f / (1.f + __expf(2.f * pg));
      float cn = fg * cr[j] + ig * gg;
      cr[j] = cn;
      hv[j] = og * (1.f - 2.f / (1.f + __expf(2.f * cn)));
    }
    if (t >= 3) {
      if (tid == 0) spin_ge(&consCnt[(t - 2) * 4 + mb], 64u);
      __syncthreads();
    }
    if (t < T_DIM - 1) {
      int hcg = cb * 16 + hb2;
      int kc2 = hcg >> 7, kp = hcg & 127;
      unsigned byte = ((unsigned)(erow * 256 + kp * 2)) ^ ((unsigned)((erow & 7) << 4));
      unsigned pk = (unsigned)f2bf(hv[0]) | ((unsigned)f2bf(hv[1]) << 16);
      unsigned int* hd = (unsigned int*)(hring + (size_t)(t % 3) * 524288 +
                                         (size_t)(mb * 8 + kc2) * BLK + byte);
      __hip_atomic_store(hd, pk, __ATOMIC_RELAXED, __HIP_MEMORY_SCOPE_AGENT);
    }
    asm volatile("s_waitcnt vmcnt(0)" ::: "memory");
    __syncthreads();
    if (tid == 0) {
      if (t < T_DIM - 1)
        __hip_atomic_fetch_add(&prodCnt[t * 4 + mb], 1u, __ATOMIC_RELEASE,
                               __HIP_MEMORY_SCOPE_AGENT);
      if (t >= 1)
        __hip_atomic_fetch_add(&consCnt[t * 4 + mb], 1u, __ATOMIC_RELAXED,
                               __HIP_MEMORY_SCOPE_AGENT);
    }
    if (t == T_DIM - 1) {
      size_t gidx = (size_t)(mb * 64 + erow) * HID_DIM + cb * 16 + hb2;
      *(float2*)(out + gidx) = make_float2(hv[0], hv[1]);
      *(float2*)(out + (size_t)B_DIM * HID_DIM + gidx) = make_float2(cr[0], cr[1]);
    }
  }
}

extern "C" void kernel_launch(void* const* d_in, const int* in_sizes, int n_in,
                              void* d_out, int out_size, void* d_ws, size_t ws_size,
                              hipStream_t stream) {
  (void)in_sizes; (void)n_in; (void)out_size;
  const float* x   = (const float*)d_in[0];
  const float* Wf_ = (const float*)d_in[1];
  const float* bf_ = (const float*)d_in[2];
  const float* Wi_ = (const float*)d_in[3];
  const float* bi_ = (const float*)d_in[4];
  const float* Wo_ = (const float*)d_in[5];
  const float* bo_ = (const float*)d_in[6];
  const float* Wc_ = (const float*)d_in[7];
  const float* bc_ = (const float*)d_in[8];
  float* out = (float*)d_out;
  unsigned char* ws = (unsigned char*)d_ws;

  // new layout
  unsigned char* Wp = ws;
  size_t off = 16777216;
  float* bp = (float*)(ws + off);                    off += 16384;
  unsigned int* prodCnt = (unsigned int*)(ws + off); off += 8192;
  unsigned int* consCnt = (unsigned int*)(ws + off); off += 8192;
  unsigned char* hring = ws + off;                   off += 3 * 524288;
  float* gxr = (float*)(ws + off);                   off += 2 * 4194304;
  unsigned char* xpp = ws + off;                     off += 268435456;
  const size_t NEED_NEW = off;

  prep_pack_w<<<1024, 256, 0, stream>>>(Wi_, Wf_, Wo_, Wc_, Wp);
  prep_bias<<<16, 256, 0, stream>>>(bi_, bf_, bo_, bc_, bp);
  hipMemsetAsync(prodCnt, 0, 16384, stream);

  if (ws_size >= NEED_NEW) {
    prep_pack_x<<<16384, 256, 0, stream>>>(x, xpp);
    hipFuncSetAttribute((const void*)lstm_ws,
                        hipFuncAttributeMaxDynamicSharedMemorySize, 131072);
    const unsigned char* a_xp = xpp;
    const unsigned char* a_wp = Wp;
    const float* a_bp = bp;
    float* a_gx = gxr;
    unsigned char* a_hr = hring;
    unsigned int* a_pc = prodCnt;
    unsigned int* a_cc = consCnt;
    float* a_out = out;
    void* args[] = {&a_xp, &a_wp, &a_bp, &a_gx, &a_hr, &a_pc, &a_cc, &a_out};
    hipLaunchCooperativeKernel((const void*)lstm_ws, dim3(256), dim3(512),
                               args, 131072u, stream);
  } else {
    // round-3 layout (no gx ring)
    unsigned char* xpp3 = ws + (NEED_NEW - 268435456 - 2 * 4194304);
    prep_pack_x<<<16384, 256, 0, stream>>>(x, xpp3);
    hipFuncSetAttribute((const void*)lstm_persist,
                        hipFuncAttributeMaxDynamicSharedMemorySize, 131072);
    const unsigned char* a_xp = xpp3;
    const unsigned char* a_wp = Wp;
    const float* a_bp = bp;
    unsigned char* a_hr = hring;
    unsigned int* a_pc = prodCnt;
    unsigned int* a_cc = consCnt;
    float* a_out = out;
    void* args[] = {&a_xp, &a_wp, &a_bp, &a_hr, &a_pc, &a_cc, &a_out};
    hipLaunchCooperativeKernel((const void*)lstm_persist, dim3(256), dim3(512),
                               args, 131072u, stream);
  }
}